// Round 16
// baseline (227.007 us; speedup 1.0000x reference)
//
#include <hip/hip_runtime.h>
#include <math.h>

#define N_NODES 50000
#define N_EDGES 800000
#define NEG_SLOPE 0.2f
#define PADU N_NODES               // pad sentinel source index (als1 row=-1e30, h8 pad row=0)
#define LOG2E 1.44269504088896f

// binned scatter params: 256-node buckets
#define BSHIFT 8
#define NBUK ((N_NODES + 255) >> BSHIFT)    // 196 buckets
#define BCAP 4608                           // per-bucket capacity (mean 4096, +8 sigma)
#define ACHUNK 4096                         // edges per k_bin block
#define BINB ((N_EDGES + ACHUNK - 1) / ACHUNK)  // 196 bin blocks
#define PADBUK 5632                         // fixed padded bucket pitch: 4608 + 4*256
#define ET_PAD_ALLOC (NBUK * PADBUK)        // 1103872 esrc entries
#define G1B ((N_NODES + 63) / 64)           // 782 gemm1 blocks (BM=64)

typedef __attribute__((ext_vector_type(8))) short s16x8;
typedef __attribute__((ext_vector_type(4))) float f32x4;
typedef __attribute__((ext_vector_type(2))) float f32x2;

__device__ __forceinline__ unsigned short f2bf(float f) {
    union { float f; unsigned u; } v; v.f = f;
    unsigned r = v.u + 0x7FFF + ((v.u >> 16) & 1);  // RNE
    return (unsigned short)(r >> 16);
}
__device__ __forceinline__ float asf(unsigned u) {
    union { unsigned u; float f; } v; v.u = u;
    return v.f;
}
// truncation-pack 8 fp32 -> 8 bf16
__device__ __forceinline__ uint4 pack_bf16_trunc(float4 f0, float4 f1) {
    const unsigned* a = (const unsigned*)&f0;
    const unsigned* b = (const unsigned*)&f1;
    uint4 r;
    r.x = (a[0] >> 16) | (a[1] & 0xffff0000u);
    r.y = (a[2] >> 16) | (a[3] & 0xffff0000u);
    r.z = (b[0] >> 16) | (b[1] & 0xffff0000u);
    r.w = (b[2] >> 16) | (b[3] & 0xffff0000u);
    return r;
}
// fp8 e4m3 (OCP) — HW convert
__device__ __forceinline__ unsigned char f2fp8(float f) {
    return (unsigned char)(__builtin_amdgcn_cvt_pk_fp8_f32(f, f, 0, false) & 0xff);
}

// ---------------- Fused kernel A: edge binning (blocks 0..195) || weight converts (196..484) ----------------
// bcur is zeroed by hipMemsetAsync before this kernel.

__global__ __launch_bounds__(256) void k_pre1(const int* __restrict__ ei, int* __restrict__ bcur,
                                              unsigned* __restrict__ stage,
                                              const float* __restrict__ W1, const float* __restrict__ W2,
                                              unsigned short* __restrict__ WT, unsigned short* __restrict__ W2T,
                                              float* __restrict__ als1, unsigned char* __restrict__ H8) {
    __shared__ unsigned sdata[ACHUNK];        // u | vloc<<16 | buk<<24, bucket-major
    __shared__ unsigned short sv[ACHUNK];     // v cached between passes (v < 65536)
    __shared__ int scnt[NBUK];
    __shared__ int soff[NBUK + 1];
    __shared__ int sgbase[NBUK];
    __shared__ int wssc[4];
    int tid = threadIdx.x;
    int blk = blockIdx.x;

    if (blk >= BINB) {
        // ---- cvtw role ----
        int b = blk - BINB;                   // 0..288
        int k = tid;
        if (b < 256) {
            WT[b * 256 + k] = f2bf(W1[k * 256 + b]);
        } else if (b < 288) {
            int c = b - 256;
            W2T[c * 256 + k] = f2bf(W2[k * 32 + c]);
        } else {
            if (k >= 196 && k < 200) als1[N_NODES * 4 + (k - 196)] = -1e30f;            // pad row: exp2 -> 0
            if (k >= 200 && k < 264) ((unsigned*)H8)[(size_t)N_NODES * 64 + (k - 200)] = 0;  // h8 pad row
        }
        return;
    }

    // ---- bin role ----
    int e0 = blk * ACHUNK;
    int nE = N_EDGES - e0;
    if (nE > ACHUNK) nE = ACHUNK;
    for (int i = tid; i < NBUK; i += 256) scnt[i] = 0;
    __syncthreads();
    for (int i = tid; i < nE; i += 256) {
        int v = ei[N_EDGES + e0 + i];
        sv[i] = (unsigned short)v;
        atomicAdd(&scnt[v >> BSHIFT], 1);
    }
    __syncthreads();
    {
        int lane = tid & 63, w = tid >> 6;
        int val = (tid < NBUK) ? scnt[tid] : 0;
        int incl = val;
        for (int o = 1; o < 64; o <<= 1) {
            int t = __shfl_up(incl, o);
            if (lane >= o) incl += t;
        }
        if (lane == 63) wssc[w] = incl;
        __syncthreads();
        int wb = 0;
        for (int i = 0; i < w; ++i) wb += wssc[i];
        if (tid < NBUK) soff[tid] = wb + incl - val;
        if (tid == 255) soff[NBUK] = wb + incl;
    }
    __syncthreads();
    if (tid < NBUK) {
        int c = scnt[tid];
        sgbase[tid] = c ? atomicAdd(&bcur[tid], c) : 0;
        scnt[tid] = soff[tid];
    }
    __syncthreads();
    for (int i = tid; i < nE; i += 256) {
        int u = ei[e0 + i];
        unsigned v = sv[i];
        int b = (int)(v >> BSHIFT);
        int pos = atomicAdd(&scnt[b], 1);
        sdata[pos] = (unsigned)u | ((v & 255u) << 16) | ((unsigned)b << 24);
    }
    __syncthreads();
    for (int i = tid; i < nE; i += 256) {
        unsigned pk = sdata[i];
        int buk = (int)(pk >> 24);
        int rel = sgbase[buk] + (i - soff[buk]);
        if (rel < BCAP) stage[(size_t)buk * BCAP + rel] = pk;
    }
}

// ---------------- Fused kernel B: GEMM1 direct-load (no LDS/barriers) || CSR build ----------------
// gemm role: A fragments packed from X in-register; B fragments read from L2-resident WT.
// Zero __syncthreads in gemm role -> waves decouple, latency hidden by scheduler.

__global__ __launch_bounds__(256) void k_pre2(const float* __restrict__ X, const unsigned short* __restrict__ WT,
                                              const float* __restrict__ a_src, const float* __restrict__ a_dst,
                                              unsigned char* __restrict__ H8,
                                              float* __restrict__ als, float* __restrict__ ald,
                                              const unsigned* __restrict__ stage, const int* __restrict__ bcur,
                                              int* __restrict__ offp, int* __restrict__ ecnt,
                                              unsigned short* __restrict__ esrc) {
    __shared__ int smraw_i[6400];   // 25600 B (build role only)
    char* smraw = (char*)smraw_i;
    int tid = threadIdx.x;

    if (blockIdx.x < G1B) {
        // ---- gemm1m role: direct-load fragments, no LDS, no barriers ----
        int row0 = blockIdx.x * 64;
        int wv = tid >> 6, lane = tid & 63;
        int wm = wv & 1, wn = wv >> 1;
        int lr = lane & 15, quad = lane >> 4;
        f32x4 acc[2][8];
#pragma unroll
        for (int mt = 0; mt < 2; ++mt)
#pragma unroll
            for (int nt = 0; nt < 8; ++nt) acc[mt][nt] = (f32x4){0.f, 0.f, 0.f, 0.f};

        int rA0 = row0 + wm * 32 + lr;              // mt=0 row
        int rA1 = rA0 + 16;                         // mt=1 row
        int cA0 = (rA0 < N_NODES) ? rA0 : (N_NODES - 1);   // clamp (epilogue guards stores)
        int cA1 = (rA1 < N_NODES) ? rA1 : (N_NODES - 1);
        const float* x0 = X + (size_t)cA0 * 256 + quad * 8;
        const float* x1 = X + (size_t)cA1 * 256 + quad * 8;
        const unsigned short* wbase = WT + (wn * 128 + lr) * 256 + quad * 8;

        for (int k0 = 0; k0 < 256; k0 += 32) {
            union { uint4 u; s16x8 s; } ca, cb;
            float4 f0 = *(const float4*)(x0 + k0);
            float4 f1 = *(const float4*)(x0 + k0 + 4);
            ca.u = pack_bf16_trunc(f0, f1);
            float4 g0 = *(const float4*)(x1 + k0);
            float4 g1 = *(const float4*)(x1 + k0 + 4);
            cb.u = pack_bf16_trunc(g0, g1);
            s16x8 a0 = ca.s, a1 = cb.s;
            s16x8 b[8];
#pragma unroll
            for (int nt = 0; nt < 8; ++nt) b[nt] = *(const s16x8*)(wbase + nt * 16 * 256 + k0);
#pragma unroll
            for (int nt = 0; nt < 8; ++nt) {
                acc[0][nt] = __builtin_amdgcn_mfma_f32_16x16x32_bf16(a0, b[nt], acc[0][nt], 0, 0, 0);
                acc[1][nt] = __builtin_amdgcn_mfma_f32_16x16x32_bf16(a1, b[nt], acc[1][nt], 0, 0, 0);
            }
        }
#pragma unroll
        for (int mt = 0; mt < 2; ++mt) {
#pragma unroll
            for (int r = 0; r < 4; ++r) {
                int row = row0 + wm * 32 + mt * 16 + quad * 4 + r;
                if (row < N_NODES) {
#pragma unroll
                    for (int nt = 0; nt < 8; ++nt) {
                        int col = wn * 128 + nt * 16 + lr;
                        H8[(size_t)row * 256 + col] = f2fp8(acc[mt][nt][r]);
                    }
                }
            }
        }
        float av[8], dv[8];
#pragma unroll
        for (int nt = 0; nt < 8; ++nt) {
            int col = wn * 128 + nt * 16 + lr;
            av[nt] = a_src[col] * LOG2E;   // pre-scale: downstream uses exp2
            dv[nt] = a_dst[col] * LOG2E;
        }
        float ps[2][8], pd[2][8];
#pragma unroll
        for (int hl = 0; hl < 2; ++hl)
#pragma unroll
            for (int i = 0; i < 8; ++i) { ps[hl][i] = 0.f; pd[hl][i] = 0.f; }
#pragma unroll
        for (int mt = 0; mt < 2; ++mt)
#pragma unroll
            for (int nt = 0; nt < 8; ++nt) {
                int hl = nt >> 2;
#pragma unroll
                for (int r = 0; r < 4; ++r) {
                    float v = acc[mt][nt][r];
                    ps[hl][mt * 4 + r] = fmaf(v, av[nt], ps[hl][mt * 4 + r]);
                    pd[hl][mt * 4 + r] = fmaf(v, dv[nt], pd[hl][mt * 4 + r]);
                }
            }
#pragma unroll
        for (int hl = 0; hl < 2; ++hl)
#pragma unroll
            for (int i = 0; i < 8; ++i) {
                float s = ps[hl][i], d = pd[hl][i];
#pragma unroll
                for (int m = 8; m >= 1; m >>= 1) { s += __shfl_xor(s, m); d += __shfl_xor(d, m); }
                if (lr == 0) {
                    int row = row0 + wm * 32 + (i >> 2) * 16 + quad * 4 + (i & 3);
                    if (row < N_NODES) {
                        als[row * 4 + wn * 2 + hl] = s;
                        ald[row * 4 + wn * 2 + hl] = d;
                    }
                }
            }
        return;
    }

    // ---- build role ----
    int* hist   = (int*)smraw;             // 256 ints  [0,1024)
    int* lexcl  = (int*)(smraw + 1024);    // 257 ints  [1024,2052)
    int* ws     = (int*)(smraw + 2052);    // 4 ints    [2052,2068)
    int* outbuf = (int*)(smraw + 2068);    // 5632 ints [2068,24596)
    int b = blockIdx.x - G1B;
    int n = bcur[b];
    if (n > BCAP) n = BCAP;
    int base = b << BSHIFT;
    int nv = N_NODES - base;
    if (nv > 256) nv = 256;
    hist[tid] = 0;
    __syncthreads();
    const unsigned* sg = stage + (size_t)b * BCAP;
    for (int i = tid; i < n; i += 256) atomicAdd(&hist[(sg[i] >> 16) & 0xFF], 1);
    __syncthreads();
    int lane = tid & 63, w = tid >> 6;
    int c = (tid < nv) ? hist[tid] + 1 : 0;       // real count incl self-loop
    int r = (tid < nv) ? ((c + 3) & ~3) : 0;      // padded to multiple of 4
    int incl = r;
    for (int o = 1; o < 64; o <<= 1) {
        int t = __shfl_up(incl, o);
        if (lane >= o) incl += t;
    }
    if (lane == 63) ws[w] = incl;
    __syncthreads();
    int wb = 0;
    for (int i = 0; i < w; ++i) wb += ws[i];
    int excl = wb + incl - r;
    lexcl[tid] = excl;
    if (tid == 255) lexcl[256] = excl + r;        // padded total
    int gb = b * PADBUK;                          // fixed pitch (4-aligned)
    if (tid < nv) {
        offp[base + tid] = gb + excl;             // 4-aligned
        ecnt[base + tid] = c;
    }
    __syncthreads();
    int total = lexcl[256];
    if (tid < nv) {
        outbuf[excl] = base + tid;                // self-loop first
        for (int j = excl + c; j < excl + r; ++j) outbuf[j] = PADU;   // pads (<=3)
        hist[tid] = 1;                            // cursor starts after self-loop
    }
    __syncthreads();
    for (int i = tid; i < n; i += 256) {
        unsigned pk = sg[i];
        int vloc = (int)((pk >> 16) & 0xFF);
        int pos = lexcl[vloc] + atomicAdd(&hist[vloc], 1);
        outbuf[pos] = (int)(pk & 0xffffu);
    }
    __syncthreads();
    for (int i = tid; i < total; i += 256) esrc[gb + i] = (unsigned short)outbuf[i];
}

// ---------------- Layer-1 aggregation: 2 nodes/wave x 32 lanes x uint2 (round-11 best) ----------------

__global__ __launch_bounds__(256) void k_agg1(const uint2* __restrict__ H8u2,
                                              const float* __restrict__ als, const float* __restrict__ ald_,
                                              const int* __restrict__ offp, const int* __restrict__ ecnt,
                                              const unsigned short* __restrict__ esrc,
                                              const float* __restrict__ b1, uint2* __restrict__ H2p2) {
    int tid = threadIdx.x;
    int wid = (blockIdx.x * 256 + tid) >> 6;          // 25000 waves
    int half = (tid >> 5) & 1;
    int node = wid * 2 + half;                        // < 50000
    int lane = tid & 31;                              // 0..31 within node group
    int head = lane >> 3;                             // channels 8*lane..8*lane+7 in one head
    float ald = ald_[node * 4 + head];
    int pstart = offp[node];
    int rend = pstart + ((ecnt[node] + 3) & ~3);
    float l = 0.f;
    f32x2 acc0 = (f32x2){0.f, 0.f}, acc1 = (f32x2){0.f, 0.f};
    f32x2 acc2 = (f32x2){0.f, 0.f}, acc3 = (f32x2){0.f, 0.f};

    auto quad = [&](unsigned ua, unsigned ub) {
        int u0 = (int)(ua & 0xffffu), u1 = (int)(ua >> 16);
        int u2 = (int)(ub & 0xffffu), u3 = (int)(ub >> 16);
        // pads (u=50000) read zeroed h8 row and -1e30 als row -> contribute 0
        uint2 v0 = H8u2[(unsigned)u0 * 32 + lane];
        uint2 v1 = H8u2[(unsigned)u1 * 32 + lane];
        uint2 v2 = H8u2[(unsigned)u2 * 32 + lane];
        uint2 v3 = H8u2[(unsigned)u3 * 32 + lane];
        f32x2 e01 = (f32x2){als[u0 * 4 + head], als[u1 * 4 + head]} + (f32x2){ald, ald};
        f32x2 e23 = (f32x2){als[u2 * 4 + head], als[u3 * 4 + head]} + (f32x2){ald, ald};
        f32x2 t01 = e01 * NEG_SLOPE, t23 = e23 * NEG_SLOPE;
        float e0 = fmaxf(e01.x, t01.x), e1 = fmaxf(e01.y, t01.y);
        float e2 = fmaxf(e23.x, t23.x), e3 = fmaxf(e23.y, t23.y);
        float pw0 = __builtin_amdgcn_exp2f(e0);   // logits pre-scaled by LOG2E
        float pw1 = __builtin_amdgcn_exp2f(e1);
        float pw2 = __builtin_amdgcn_exp2f(e2);
        float pw3 = __builtin_amdgcn_exp2f(e3);
        l += (pw0 + pw1) + (pw2 + pw3);
        f32x2 w0 = (f32x2){pw0, pw0}, w1 = (f32x2){pw1, pw1};
        f32x2 w2 = (f32x2){pw2, pw2}, w3 = (f32x2){pw3, pw3};
        acc0 += w0 * __builtin_amdgcn_cvt_pk_f32_fp8(v0.x, false);
        acc1 += w0 * __builtin_amdgcn_cvt_pk_f32_fp8(v0.x, true);
        acc2 += w0 * __builtin_amdgcn_cvt_pk_f32_fp8(v0.y, false);
        acc3 += w0 * __builtin_amdgcn_cvt_pk_f32_fp8(v0.y, true);
        acc0 += w1 * __builtin_amdgcn_cvt_pk_f32_fp8(v1.x, false);
        acc1 += w1 * __builtin_amdgcn_cvt_pk_f32_fp8(v1.x, true);
        acc2 += w1 * __builtin_amdgcn_cvt_pk_f32_fp8(v1.y, false);
        acc3 += w1 * __builtin_amdgcn_cvt_pk_f32_fp8(v1.y, true);
        acc0 += w2 * __builtin_amdgcn_cvt_pk_f32_fp8(v2.x, false);
        acc1 += w2 * __builtin_amdgcn_cvt_pk_f32_fp8(v2.x, true);
        acc2 += w2 * __builtin_amdgcn_cvt_pk_f32_fp8(v2.y, false);
        acc3 += w2 * __builtin_amdgcn_cvt_pk_f32_fp8(v2.y, true);
        acc0 += w3 * __builtin_amdgcn_cvt_pk_f32_fp8(v3.x, false);
        acc1 += w3 * __builtin_amdgcn_cvt_pk_f32_fp8(v3.x, true);
        acc2 += w3 * __builtin_amdgcn_cvt_pk_f32_fp8(v3.y, false);
        acc3 += w3 * __builtin_amdgcn_cvt_pk_f32_fp8(v3.y, true);
    };

    int p = pstart;
    for (; p + 7 < rend; p += 8) {
        uint2 ua = *(const uint2*)(esrc + p);
        uint2 ub = *(const uint2*)(esrc + p + 4);
        quad(ua.x, ua.y);
        quad(ub.x, ub.y);
    }
    if (p < rend) {
        uint2 ua = *(const uint2*)(esrc + p);
        quad(ua.x, ua.y);
    }

    float inv = 1.f / l;
    int c = lane * 8;
    float4 bb0 = *(const float4*)(b1 + c);
    float4 bb1 = *(const float4*)(b1 + c + 4);
    float o0 = acc0.x * inv + bb0.x, o1 = acc0.y * inv + bb0.y;
    float o2 = acc1.x * inv + bb0.z, o3 = acc1.y * inv + bb0.w;
    float o4 = acc2.x * inv + bb1.x, o5 = acc2.y * inv + bb1.y;
    float o6 = acc3.x * inv + bb1.z, o7 = acc3.y * inv + bb1.w;
    o0 = o0 > 0.f ? o0 : expm1f(o0);
    o1 = o1 > 0.f ? o1 : expm1f(o1);
    o2 = o2 > 0.f ? o2 : expm1f(o2);
    o3 = o3 > 0.f ? o3 : expm1f(o3);
    o4 = o4 > 0.f ? o4 : expm1f(o4);
    o5 = o5 > 0.f ? o5 : expm1f(o5);
    o6 = o6 > 0.f ? o6 : expm1f(o6);
    o7 = o7 > 0.f ? o7 : expm1f(o7);
    unsigned pkx = __builtin_amdgcn_cvt_pk_fp8_f32(o0, o1, 0, false);
    pkx = __builtin_amdgcn_cvt_pk_fp8_f32(o2, o3, pkx, true);
    unsigned pky = __builtin_amdgcn_cvt_pk_fp8_f32(o4, o5, 0, false);
    pky = __builtin_amdgcn_cvt_pk_fp8_f32(o6, o7, pky, true);
    H2p2[(unsigned)node * 32 + lane] = make_uint2(pkx, pky);
}

// ---------------- GEMM2 via MFMA: g = h2(fp8->bf16) @ W2(bf16) + layer-2 logits (pre-scaled) ----------------

__global__ __launch_bounds__(256) void k_gemm2m(const unsigned* __restrict__ H2p,
                                                const unsigned short* __restrict__ W2T,
                                                const float* __restrict__ as2, const float* __restrict__ ad2,
                                                unsigned short* __restrict__ Gb, float* __restrict__ als2,
                                                float* __restrict__ ald2) {
    int tid = threadIdx.x;
    int wv = tid >> 6, lane = tid & 63, lr = lane & 15, quad = lane >> 4;
    int row0 = blockIdx.x * 64 + wv * 16;
    int rowA = row0 + lr;
    unsigned rA = (rowA < N_NODES) ? (unsigned)rowA : (unsigned)(N_NODES - 1);
    f32x4 acc[2];
    acc[0] = (f32x4){0.f, 0.f, 0.f, 0.f};
    acc[1] = (f32x4){0.f, 0.f, 0.f, 0.f};
#pragma unroll
    for (int k0 = 0; k0 < 256; k0 += 32) {
        uint2 d = *(const uint2*)(H2p + rA * 64 + (k0 >> 2) + quad * 2);
        f32x2 f0 = __builtin_amdgcn_cvt_pk_f32_fp8(d.x, false);
        f32x2 f1 = __builtin_amdgcn_cvt_pk_f32_fp8(d.x, true);
        f32x2 f2 = __builtin_amdgcn_cvt_pk_f32_fp8(d.y, false);
        f32x2 f3 = __builtin_amdgcn_cvt_pk_f32_fp8(d.y, true);
        union { uint4 u; s16x8 s; } cv;
        cv.u = pack_bf16_trunc(make_float4(f0.x, f0.y, f1.x, f1.y), make_float4(f2.x, f2.y, f3.x, f3.y));
        s16x8 afrag = cv.s;
        s16x8 b0 = *(const s16x8*)(W2T + lr * 256 + k0 + quad * 8);
        s16x8 b1f = *(const s16x8*)(W2T + (16 + lr) * 256 + k0 + quad * 8);
        acc[0] = __builtin_amdgcn_mfma_f32_16x16x32_bf16(afrag, b0, acc[0], 0, 0, 0);
        acc[1] = __builtin_amdgcn_mfma_f32_16x16x32_bf16(afrag, b1f, acc[1], 0, 0, 0);
    }
    float a2s = as2[lr] * LOG2E, a2s2 = as2[16 + lr] * LOG2E;
    float a2d = ad2[lr] * LOG2E, a2d2 = ad2[16 + lr] * LOG2E;
#pragma unroll
    for (int r = 0; r < 4; ++r) {
        int row = row0 + quad * 4 + r;
        float g0 = acc[0][r], g1 = acc[1][r];
        float s = g0 * a2s + g1 * a2s2;
        float dd = g0 * a2d + g1 * a2d2;
#pragma unroll
        for (int m = 8; m >= 1; m >>= 1) { s += __shfl_xor(s, m); dd += __shfl_xor(dd, m); }
        if (row < N_NODES) {
            Gb[(size_t)row * 32 + lr] = f2bf(g0);
            Gb[(size_t)row * 32 + 16 + lr] = f2bf(g1);
            if (lr == 0) { als2[row] = s; ald2[row] = dd; }
        }
    }
}

// ---------------- Layer-2 aggregation: 16 lanes/node x 2 cols, pk-fma, direct v_exp (round-11 best) --------

__global__ __launch_bounds__(256) void k_agg2(const unsigned short* __restrict__ Gb,
                                              const float* __restrict__ als2,
                                              const float* __restrict__ ald2_, const int* __restrict__ offp,
                                              const int* __restrict__ ecnt,
                                              const unsigned short* __restrict__ esrc, const float* __restrict__ b2,
                                              float* __restrict__ out) {
    int gid = blockIdx.x * 256 + threadIdx.x;
    int node = gid >> 4;
    int colp = gid & 15;            // cols 2*colp, 2*colp+1
    if (node >= N_NODES) return;
    float ald = ald2_[node];        // pre-scaled by LOG2E
    int pstart = offp[node];        // 4-aligned
    int pend = pstart + ecnt[node]; // real end (pads excluded)
    float l = 0.f;
    f32x2 accv = (f32x2){0.f, 0.f};

    auto edge1 = [&](int u0) {
        unsigned gpk = *(const unsigned*)(Gb + (size_t)(unsigned)u0 * 32 + 2 * colp);
        f32x2 g01 = (f32x2){asf(gpk << 16), asf(gpk & 0xffff0000u)};
        float e0 = als2[u0] + ald;
        e0 = fmaxf(e0, NEG_SLOPE * e0);
        float pw0 = __builtin_amdgcn_exp2f(e0);
        l += pw0;
        accv += (f32x2){pw0, pw0} * g01;
    };
    auto quad = [&](unsigned ua, unsigned ub) {
        int u0 = (int)(ua & 0xffffu), u1 = (int)(ua >> 16);
        int u2 = (int)(ub & 0xffffu), u3 = (int)(ub >> 16);
        unsigned g0p = *(const unsigned*)(Gb + (size_t)(unsigned)u0 * 32 + 2 * colp);
        unsigned g1p = *(const unsigned*)(Gb + (size_t)(unsigned)u1 * 32 + 2 * colp);
        unsigned g2p = *(const unsigned*)(Gb + (size_t)(unsigned)u2 * 32 + 2 * colp);
        unsigned g3p = *(const unsigned*)(Gb + (size_t)(unsigned)u3 * 32 + 2 * colp);
        f32x2 e01 = (f32x2){als2[u0], als2[u1]} + (f32x2){ald, ald};
        f32x2 e23 = (f32x2){als2[u2], als2[u3]} + (f32x2){ald, ald};
        f32x2 t01 = e01 * NEG_SLOPE, t23 = e23 * NEG_SLOPE;
        float e0 = fmaxf(e01.x, t01.x), e1 = fmaxf(e01.y, t01.y);
        float e2 = fmaxf(e23.x, t23.x), e3 = fmaxf(e23.y, t23.y);
        float pw0 = __builtin_amdgcn_exp2f(e0), pw1 = __builtin_amdgcn_exp2f(e1);
        float pw2 = __builtin_amdgcn_exp2f(e2), pw3 = __builtin_amdgcn_exp2f(e3);
        l += (pw0 + pw1) + (pw2 + pw3);
        f32x2 g0 = (f32x2){asf(g0p << 16), asf(g0p & 0xffff0000u)};
        f32x2 g1 = (f32x2){asf(g1p << 16), asf(g1p & 0xffff0000u)};
        f32x2 g2 = (f32x2){asf(g2p << 16), asf(g2p & 0xffff0000u)};
        f32x2 g3 = (f32x2){asf(g3p << 16), asf(g3p & 0xffff0000u)};
        accv += (f32x2){pw0, pw0} * g0;
        accv += (f32x2){pw1, pw1} * g1;
        accv += (f32x2){pw2, pw2} * g2;
        accv += (f32x2){pw3, pw3} * g3;
    };

    int p = pstart;
    for (; p + 7 < pend; p += 8) {
        uint2 ua = *(const uint2*)(esrc + p);
        uint2 ub = *(const uint2*)(esrc + p + 4);
        quad(ua.x, ua.y);
        quad(ub.x, ub.y);
    }
    for (; p + 3 < pend; p += 4) {
        uint2 ua = *(const uint2*)(esrc + p);
        quad(ua.x, ua.y);
    }
    for (; p < pend; ++p) edge1(esrc[p]);

    float inv = 1.f / l;
    float2 bb = *(const float2*)(b2 + 2 * colp);
    float o0 = accv.x * inv + bb.x;
    float o1 = accv.y * inv + bb.y;
    float mm = fmaxf(o0, o1);
#pragma unroll
    for (int msk = 8; msk >= 1; msk >>= 1) mm = fmaxf(mm, __shfl_xor(mm, msk));
    float s = __expf(o0 - mm) + __expf(o1 - mm);
#pragma unroll
    for (int msk = 8; msk >= 1; msk >>= 1) s += __shfl_xor(s, msk);
    float ls = logf(s);
    float2 res = make_float2(o0 - mm - ls, o1 - mm - ls);
    *(float2*)(out + (size_t)node * 32 + 2 * colp) = res;
}

// ---------------- launch ----------------

extern "C" void kernel_launch(void* const* d_in, const int* in_sizes, int n_in,
                              void* d_out, int out_size, void* d_ws, size_t ws_size,
                              hipStream_t stream) {
    const float* x   = (const float*)d_in[0];
    const int*   ei  = (const int*)d_in[1];
    const float* W1  = (const float*)d_in[2];
    const float* as1 = (const float*)d_in[3];
    const float* ad1 = (const float*)d_in[4];
    const float* b1  = (const float*)d_in[5];
    const float* W2  = (const float*)d_in[6];
    const float* as2 = (const float*)d_in[7];
    const float* ad2 = (const float*)d_in[8];
    const float* b2  = (const float*)d_in[9];
    float* out = (float*)d_out;

    char* p = (char*)d_ws;
    auto alloc = [&](size_t bytes) {
        char* r = p;
        p += (bytes + 255) & ~(size_t)255;
        return r;
    };
    // workspace ~30 MB (stage aliases h2p; g aliases h8 — disjoint lifetimes)
    unsigned char*  h8  = (unsigned char*)alloc((size_t)(N_NODES + 1) * 256);  // 12.8 MB fp8 h1 (+pad row)
    unsigned char*  h2pr= (unsigned char*)alloc((size_t)N_NODES * 64 * 4);     // 12.8 MB fp8 h2 packed
    unsigned short* wt  = (unsigned short*)alloc((size_t)256 * 256 * 2);       // 128 KB bf16 W1^T
    unsigned short* w2t = (unsigned short*)alloc((size_t)32 * 256 * 2);        // 16 KB bf16 W2^T
    float* als1 = (float*)alloc(((size_t)N_NODES * 4 + 4) * 4);                // +1 pad-sentinel row
    float* ald1 = (float*)alloc((size_t)N_NODES * 4 * 4);
    float* als2 = (float*)alloc((size_t)N_NODES * 4);
    float* ald2 = (float*)alloc((size_t)N_NODES * 4);
    int* bcur    = (int*)alloc(256 * 4);
    int* offp = (int*)alloc((size_t)N_NODES * 4);
    int* ecnt = (int*)alloc((size_t)N_NODES * 4);
    unsigned short* esrc = (unsigned short*)alloc((size_t)ET_PAD_ALLOC * 2);   // 2.2 MB u16, fixed-pitch padded CSR

    // aliases (disjoint lifetimes):
    unsigned* stage = (unsigned*)h2pr;                 // 3.6 MB (pre1 -> pre2; dead before agg1 writes h2p)
    unsigned* h2p = (unsigned*)h2pr;
    unsigned short* g = (unsigned short*)h8;           // 3.2 MB bf16 (written by gemm2m after h8 dead)

    hipMemsetAsync(bcur, 0, 256 * 4, stream);                                   // bcur=0 before pre1
    k_pre1<<<BINB + 289, 256, 0, stream>>>(ei, bcur, stage, W1, W2, wt, w2t, als1, h8);
    k_pre2<<<G1B + NBUK, 256, 0, stream>>>(x, wt, as1, ad1, h8, als1, ald1, stage, bcur, offp, ecnt, esrc);
    k_agg1<<<(N_NODES / 2 + 3) / 4, 256, 0, stream>>>((const uint2*)h8, als1, ald1, offp, ecnt, esrc, b1,
                                                      (uint2*)h2p);
    k_gemm2m<<<(N_NODES + 63) / 64, 256, 0, stream>>>(h2p, w2t, as2, ad2, g, als2, ald2);
    k_agg2<<<(N_NODES * 16 + 255) / 256, 256, 0, stream>>>(g, als2, ald2, offp, ecnt, esrc, b2, out);
}

// Round 17
// 206.984 us; speedup vs baseline: 1.0967x; 1.0967x over previous
//
#include <hip/hip_runtime.h>
#include <math.h>

#define N_NODES 50000
#define N_EDGES 800000
#define NEG_SLOPE 0.2f
#define PADU N_NODES               // pad sentinel source index (als1 row=-1e30, h8 pad row=0)
#define LOG2E 1.44269504088896f

// binned scatter params: 256-node buckets
#define BSHIFT 8
#define NBUK ((N_NODES + 255) >> BSHIFT)    // 196 buckets
#define BCAP 4608                           // per-bucket capacity (mean 4096, +8 sigma)
#define ACHUNK 4096                         // edges per k_bin block
#define BINB ((N_EDGES + ACHUNK - 1) / ACHUNK)  // 196 bin blocks
#define PADBUK 5632                         // fixed padded bucket pitch: 4608 + 4*256
#define ET_PAD_ALLOC (NBUK * PADBUK)        // 1103872 esrc entries
#define G1B ((N_NODES + 31) / 32)           // 1563 gemm1 blocks (BM=32: occupancy > per-wave efficiency)

typedef __attribute__((ext_vector_type(8))) short s16x8;
typedef __attribute__((ext_vector_type(4))) float f32x4;
typedef __attribute__((ext_vector_type(2))) float f32x2;

__device__ __forceinline__ unsigned short f2bf(float f) {
    union { float f; unsigned u; } v; v.f = f;
    unsigned r = v.u + 0x7FFF + ((v.u >> 16) & 1);  // RNE
    return (unsigned short)(r >> 16);
}
__device__ __forceinline__ float asf(unsigned u) {
    union { unsigned u; float f; } v; v.u = u;
    return v.f;
}
// truncation-pack 8 fp32 -> 8 bf16
__device__ __forceinline__ uint4 pack_bf16_trunc(float4 f0, float4 f1) {
    const unsigned* a = (const unsigned*)&f0;
    const unsigned* b = (const unsigned*)&f1;
    uint4 r;
    r.x = (a[0] >> 16) | (a[1] & 0xffff0000u);
    r.y = (a[2] >> 16) | (a[3] & 0xffff0000u);
    r.z = (b[0] >> 16) | (b[1] & 0xffff0000u);
    r.w = (b[2] >> 16) | (b[3] & 0xffff0000u);
    return r;
}
// truncation-pack 4 fp32 -> 4 bf16
__device__ __forceinline__ uint2 pack_bf16_trunc4(float4 f0) {
    const unsigned* a = (const unsigned*)&f0;
    uint2 r;
    r.x = (a[0] >> 16) | (a[1] & 0xffff0000u);
    r.y = (a[2] >> 16) | (a[3] & 0xffff0000u);
    return r;
}
// fp8 e4m3 (OCP) — HW convert
__device__ __forceinline__ unsigned char f2fp8(float f) {
    return (unsigned char)(__builtin_amdgcn_cvt_pk_fp8_f32(f, f, 0, false) & 0xff);
}

// ---------------- Fused kernel A: edge binning (blocks 0..195) || weight converts (196..484) ----------------
// bcur is zeroed by hipMemsetAsync before this kernel.

__global__ __launch_bounds__(256) void k_pre1(const int* __restrict__ ei, int* __restrict__ bcur,
                                              unsigned* __restrict__ stage,
                                              const float* __restrict__ W1, const float* __restrict__ W2,
                                              unsigned short* __restrict__ WT, unsigned short* __restrict__ W2T,
                                              float* __restrict__ als1, unsigned char* __restrict__ H8) {
    __shared__ unsigned sdata[ACHUNK];        // u | vloc<<16 | buk<<24, bucket-major
    __shared__ unsigned short sv[ACHUNK];     // v cached between passes (v < 65536)
    __shared__ int scnt[NBUK];
    __shared__ int soff[NBUK + 1];
    __shared__ int sgbase[NBUK];
    __shared__ int wssc[4];
    int tid = threadIdx.x;
    int blk = blockIdx.x;

    if (blk >= BINB) {
        // ---- cvtw role ----
        int b = blk - BINB;                   // 0..288
        int k = tid;
        if (b < 256) {
            WT[b * 256 + k] = f2bf(W1[k * 256 + b]);
        } else if (b < 288) {
            int c = b - 256;
            W2T[c * 256 + k] = f2bf(W2[k * 32 + c]);
        } else {
            if (k >= 196 && k < 200) als1[N_NODES * 4 + (k - 196)] = -1e30f;            // pad row: exp2 -> 0
            if (k >= 200 && k < 264) ((unsigned*)H8)[(size_t)N_NODES * 64 + (k - 200)] = 0;  // h8 pad row
        }
        return;
    }

    // ---- bin role ----
    int e0 = blk * ACHUNK;
    int nE = N_EDGES - e0;
    if (nE > ACHUNK) nE = ACHUNK;
    for (int i = tid; i < NBUK; i += 256) scnt[i] = 0;
    __syncthreads();
    for (int i = tid; i < nE; i += 256) {
        int v = ei[N_EDGES + e0 + i];
        sv[i] = (unsigned short)v;
        atomicAdd(&scnt[v >> BSHIFT], 1);
    }
    __syncthreads();
    {
        int lane = tid & 63, w = tid >> 6;
        int val = (tid < NBUK) ? scnt[tid] : 0;
        int incl = val;
        for (int o = 1; o < 64; o <<= 1) {
            int t = __shfl_up(incl, o);
            if (lane >= o) incl += t;
        }
        if (lane == 63) wssc[w] = incl;
        __syncthreads();
        int wb = 0;
        for (int i = 0; i < w; ++i) wb += wssc[i];
        if (tid < NBUK) soff[tid] = wb + incl - val;
        if (tid == 255) soff[NBUK] = wb + incl;
    }
    __syncthreads();
    if (tid < NBUK) {
        int c = scnt[tid];
        sgbase[tid] = c ? atomicAdd(&bcur[tid], c) : 0;
        scnt[tid] = soff[tid];
    }
    __syncthreads();
    for (int i = tid; i < nE; i += 256) {
        int u = ei[e0 + i];
        unsigned v = sv[i];
        int b = (int)(v >> BSHIFT);
        int pos = atomicAdd(&scnt[b], 1);
        sdata[pos] = (unsigned)u | ((v & 255u) << 16) | ((unsigned)b << 24);
    }
    __syncthreads();
    for (int i = tid; i < nE; i += 256) {
        unsigned pk = sdata[i];
        int buk = (int)(pk >> 24);
        int rel = sgbase[buk] + (i - soff[buk]);
        if (rel < BCAP) stage[(size_t)buk * BCAP + rel] = pk;
    }
}

// ---------------- Fused kernel B: GEMM1 BM=32 (occupancy-first) || CSR build ----------------
// LDS union: gemm role 23.0KB As/Bs; build role 24.6KB hist/lexcl/ws/outbuf.

__global__ __launch_bounds__(256) void k_pre2(const float* __restrict__ X, const unsigned short* __restrict__ WT,
                                              const float* __restrict__ a_src, const float* __restrict__ a_dst,
                                              unsigned char* __restrict__ H8,
                                              float* __restrict__ als, float* __restrict__ ald,
                                              const unsigned* __restrict__ stage, const int* __restrict__ bcur,
                                              int* __restrict__ offp, int* __restrict__ ecnt,
                                              unsigned short* __restrict__ esrc) {
    __shared__ int smraw_i[6400];   // 25600 B, role-unioned
    char* smraw = (char*)smraw_i;
    int tid = threadIdx.x;

    if (blockIdx.x < G1B) {
        // ---- gemm1m role: BM=32, BN=256, BK=32; 4 waves (2 row-halves x 2 col-halves) ----
        unsigned short (*As)[40] = (unsigned short(*)[40])smraw;            // 32x40 = 2560 B
        unsigned short (*Bs)[40] = (unsigned short(*)[40])(smraw + 2560);   // 256x40 = 20480 B
        int row0 = blockIdx.x * 32;
        int wv = tid >> 6, lane = tid & 63;
        int wm = wv & 1, wn = wv >> 1;
        int lr = lane & 15, quad = lane >> 4;
        f32x4 acc[8];
#pragma unroll
        for (int nt = 0; nt < 8; ++nt) acc[nt] = (f32x4){0.f, 0.f, 0.f, 0.f};

        int ar = tid >> 3, aseg = tid & 7;    // 32 rows x 8 segs of 4 floats
        for (int k0 = 0; k0 < 256; k0 += 32) {
            {
                int grow = row0 + ar;
                float4 f0 = make_float4(0.f, 0.f, 0.f, 0.f);
                if (grow < N_NODES) f0 = *(const float4*)(X + (size_t)grow * 256 + k0 + aseg * 4);
                *(uint2*)&As[ar][aseg * 4] = pack_bf16_trunc4(f0);
            }
#pragma unroll
            for (int pass = 0; pass < 4; ++pass) {
                int q = tid + pass * 256;
                int n = q >> 2, seg = q & 3;
                uint4 v = *(const uint4*)(WT + (n << 8) + k0 + seg * 8);
                *(uint4*)&Bs[n][seg * 8] = v;
            }
            __syncthreads();
            s16x8 a = *(const s16x8*)&As[wm * 16 + lr][quad * 8];
            s16x8 b[8];
#pragma unroll
            for (int nt = 0; nt < 8; ++nt) b[nt] = *(const s16x8*)&Bs[wn * 128 + nt * 16 + lr][quad * 8];
#pragma unroll
            for (int nt = 0; nt < 8; ++nt)
                acc[nt] = __builtin_amdgcn_mfma_f32_16x16x32_bf16(a, b[nt], acc[nt], 0, 0, 0);
            __syncthreads();
        }
#pragma unroll
        for (int r = 0; r < 4; ++r) {
            int row = row0 + wm * 16 + quad * 4 + r;
            if (row < N_NODES) {
#pragma unroll
                for (int nt = 0; nt < 8; ++nt) {
                    int col = wn * 128 + nt * 16 + lr;
                    H8[(size_t)row * 256 + col] = f2fp8(acc[nt][r]);
                }
            }
        }
        float av[8], dv[8];
#pragma unroll
        for (int nt = 0; nt < 8; ++nt) {
            int col = wn * 128 + nt * 16 + lr;
            av[nt] = a_src[col] * LOG2E;   // pre-scale: downstream uses exp2
            dv[nt] = a_dst[col] * LOG2E;
        }
        float ps[2][4], pd[2][4];
#pragma unroll
        for (int hl = 0; hl < 2; ++hl)
#pragma unroll
            for (int i = 0; i < 4; ++i) { ps[hl][i] = 0.f; pd[hl][i] = 0.f; }
#pragma unroll
        for (int nt = 0; nt < 8; ++nt) {
            int hl = nt >> 2;
#pragma unroll
            for (int r = 0; r < 4; ++r) {
                float v = acc[nt][r];
                ps[hl][r] = fmaf(v, av[nt], ps[hl][r]);
                pd[hl][r] = fmaf(v, dv[nt], pd[hl][r]);
            }
        }
#pragma unroll
        for (int hl = 0; hl < 2; ++hl)
#pragma unroll
            for (int i = 0; i < 4; ++i) {
                float s = ps[hl][i], d = pd[hl][i];
#pragma unroll
                for (int m = 8; m >= 1; m >>= 1) { s += __shfl_xor(s, m); d += __shfl_xor(d, m); }
                if (lr == 0) {
                    int row = row0 + wm * 16 + quad * 4 + i;
                    if (row < N_NODES) {
                        als[row * 4 + wn * 2 + hl] = s;
                        ald[row * 4 + wn * 2 + hl] = d;
                    }
                }
            }
        return;
    }

    // ---- build role ----
    int* hist   = (int*)smraw;             // 256 ints  [0,1024)
    int* lexcl  = (int*)(smraw + 1024);    // 257 ints  [1024,2052)
    int* ws     = (int*)(smraw + 2052);    // 4 ints    [2052,2068)
    int* outbuf = (int*)(smraw + 2068);    // 5632 ints [2068,24596)
    int b = blockIdx.x - G1B;
    int n = bcur[b];
    if (n > BCAP) n = BCAP;
    int base = b << BSHIFT;
    int nv = N_NODES - base;
    if (nv > 256) nv = 256;
    hist[tid] = 0;
    __syncthreads();
    const unsigned* sg = stage + (size_t)b * BCAP;
    for (int i = tid; i < n; i += 256) atomicAdd(&hist[(sg[i] >> 16) & 0xFF], 1);
    __syncthreads();
    int lane = tid & 63, w = tid >> 6;
    int c = (tid < nv) ? hist[tid] + 1 : 0;       // real count incl self-loop
    int r = (tid < nv) ? ((c + 3) & ~3) : 0;      // padded to multiple of 4
    int incl = r;
    for (int o = 1; o < 64; o <<= 1) {
        int t = __shfl_up(incl, o);
        if (lane >= o) incl += t;
    }
    if (lane == 63) ws[w] = incl;
    __syncthreads();
    int wb = 0;
    for (int i = 0; i < w; ++i) wb += ws[i];
    int excl = wb + incl - r;
    lexcl[tid] = excl;
    if (tid == 255) lexcl[256] = excl + r;        // padded total
    int gb = b * PADBUK;                          // fixed pitch (4-aligned)
    if (tid < nv) {
        offp[base + tid] = gb + excl;             // 4-aligned
        ecnt[base + tid] = c;
    }
    __syncthreads();
    int total = lexcl[256];
    if (tid < nv) {
        outbuf[excl] = base + tid;                // self-loop first
        for (int j = excl + c; j < excl + r; ++j) outbuf[j] = PADU;   // pads (<=3)
        hist[tid] = 1;                            // cursor starts after self-loop
    }
    __syncthreads();
    for (int i = tid; i < n; i += 256) {
        unsigned pk = sg[i];
        int vloc = (int)((pk >> 16) & 0xFF);
        int pos = lexcl[vloc] + atomicAdd(&hist[vloc], 1);
        outbuf[pos] = (int)(pk & 0xffffu);
    }
    __syncthreads();
    for (int i = tid; i < total; i += 256) esrc[gb + i] = (unsigned short)outbuf[i];
}

// ---------------- Layer-1 aggregation: 2 nodes/wave x 32 lanes x uint2 (round-11 best) ----------------

__global__ __launch_bounds__(256) void k_agg1(const uint2* __restrict__ H8u2,
                                              const float* __restrict__ als, const float* __restrict__ ald_,
                                              const int* __restrict__ offp, const int* __restrict__ ecnt,
                                              const unsigned short* __restrict__ esrc,
                                              const float* __restrict__ b1, uint2* __restrict__ H2p2) {
    int tid = threadIdx.x;
    int wid = (blockIdx.x * 256 + tid) >> 6;          // 25000 waves
    int half = (tid >> 5) & 1;
    int node = wid * 2 + half;                        // < 50000
    int lane = tid & 31;                              // 0..31 within node group
    int head = lane >> 3;                             // channels 8*lane..8*lane+7 in one head
    float ald = ald_[node * 4 + head];
    int pstart = offp[node];
    int rend = pstart + ((ecnt[node] + 3) & ~3);
    float l = 0.f;
    f32x2 acc0 = (f32x2){0.f, 0.f}, acc1 = (f32x2){0.f, 0.f};
    f32x2 acc2 = (f32x2){0.f, 0.f}, acc3 = (f32x2){0.f, 0.f};

    auto quad = [&](unsigned ua, unsigned ub) {
        int u0 = (int)(ua & 0xffffu), u1 = (int)(ua >> 16);
        int u2 = (int)(ub & 0xffffu), u3 = (int)(ub >> 16);
        // pads (u=50000) read zeroed h8 row and -1e30 als row -> contribute 0
        uint2 v0 = H8u2[(unsigned)u0 * 32 + lane];
        uint2 v1 = H8u2[(unsigned)u1 * 32 + lane];
        uint2 v2 = H8u2[(unsigned)u2 * 32 + lane];
        uint2 v3 = H8u2[(unsigned)u3 * 32 + lane];
        f32x2 e01 = (f32x2){als[u0 * 4 + head], als[u1 * 4 + head]} + (f32x2){ald, ald};
        f32x2 e23 = (f32x2){als[u2 * 4 + head], als[u3 * 4 + head]} + (f32x2){ald, ald};
        f32x2 t01 = e01 * NEG_SLOPE, t23 = e23 * NEG_SLOPE;
        float e0 = fmaxf(e01.x, t01.x), e1 = fmaxf(e01.y, t01.y);
        float e2 = fmaxf(e23.x, t23.x), e3 = fmaxf(e23.y, t23.y);
        float pw0 = __builtin_amdgcn_exp2f(e0);   // logits pre-scaled by LOG2E
        float pw1 = __builtin_amdgcn_exp2f(e1);
        float pw2 = __builtin_amdgcn_exp2f(e2);
        float pw3 = __builtin_amdgcn_exp2f(e3);
        l += (pw0 + pw1) + (pw2 + pw3);
        f32x2 w0 = (f32x2){pw0, pw0}, w1 = (f32x2){pw1, pw1};
        f32x2 w2 = (f32x2){pw2, pw2}, w3 = (f32x2){pw3, pw3};
        acc0 += w0 * __builtin_amdgcn_cvt_pk_f32_fp8(v0.x, false);
        acc1 += w0 * __builtin_amdgcn_cvt_pk_f32_fp8(v0.x, true);
        acc2 += w0 * __builtin_amdgcn_cvt_pk_f32_fp8(v0.y, false);
        acc3 += w0 * __builtin_amdgcn_cvt_pk_f32_fp8(v0.y, true);
        acc0 += w1 * __builtin_amdgcn_cvt_pk_f32_fp8(v1.x, false);
        acc1 += w1 * __builtin_amdgcn_cvt_pk_f32_fp8(v1.x, true);
        acc2 += w1 * __builtin_amdgcn_cvt_pk_f32_fp8(v1.y, false);
        acc3 += w1 * __builtin_amdgcn_cvt_pk_f32_fp8(v1.y, true);
        acc0 += w2 * __builtin_amdgcn_cvt_pk_f32_fp8(v2.x, false);
        acc1 += w2 * __builtin_amdgcn_cvt_pk_f32_fp8(v2.x, true);
        acc2 += w2 * __builtin_amdgcn_cvt_pk_f32_fp8(v2.y, false);
        acc3 += w2 * __builtin_amdgcn_cvt_pk_f32_fp8(v2.y, true);
        acc0 += w3 * __builtin_amdgcn_cvt_pk_f32_fp8(v3.x, false);
        acc1 += w3 * __builtin_amdgcn_cvt_pk_f32_fp8(v3.x, true);
        acc2 += w3 * __builtin_amdgcn_cvt_pk_f32_fp8(v3.y, false);
        acc3 += w3 * __builtin_amdgcn_cvt_pk_f32_fp8(v3.y, true);
    };

    int p = pstart;
    for (; p + 7 < rend; p += 8) {
        uint2 ua = *(const uint2*)(esrc + p);
        uint2 ub = *(const uint2*)(esrc + p + 4);
        quad(ua.x, ua.y);
        quad(ub.x, ub.y);
    }
    if (p < rend) {
        uint2 ua = *(const uint2*)(esrc + p);
        quad(ua.x, ua.y);
    }

    float inv = 1.f / l;
    int c = lane * 8;
    float4 bb0 = *(const float4*)(b1 + c);
    float4 bb1 = *(const float4*)(b1 + c + 4);
    float o0 = acc0.x * inv + bb0.x, o1 = acc0.y * inv + bb0.y;
    float o2 = acc1.x * inv + bb0.z, o3 = acc1.y * inv + bb0.w;
    float o4 = acc2.x * inv + bb1.x, o5 = acc2.y * inv + bb1.y;
    float o6 = acc3.x * inv + bb1.z, o7 = acc3.y * inv + bb1.w;
    o0 = o0 > 0.f ? o0 : expm1f(o0);
    o1 = o1 > 0.f ? o1 : expm1f(o1);
    o2 = o2 > 0.f ? o2 : expm1f(o2);
    o3 = o3 > 0.f ? o3 : expm1f(o3);
    o4 = o4 > 0.f ? o4 : expm1f(o4);
    o5 = o5 > 0.f ? o5 : expm1f(o5);
    o6 = o6 > 0.f ? o6 : expm1f(o6);
    o7 = o7 > 0.f ? o7 : expm1f(o7);
    unsigned pkx = __builtin_amdgcn_cvt_pk_fp8_f32(o0, o1, 0, false);
    pkx = __builtin_amdgcn_cvt_pk_fp8_f32(o2, o3, pkx, true);
    unsigned pky = __builtin_amdgcn_cvt_pk_fp8_f32(o4, o5, 0, false);
    pky = __builtin_amdgcn_cvt_pk_fp8_f32(o6, o7, pky, true);
    H2p2[(unsigned)node * 32 + lane] = make_uint2(pkx, pky);
}

// ---------------- GEMM2 via MFMA: g = h2(fp8->bf16) @ W2(bf16) + layer-2 logits (pre-scaled) ----------------

__global__ __launch_bounds__(256) void k_gemm2m(const unsigned* __restrict__ H2p,
                                                const unsigned short* __restrict__ W2T,
                                                const float* __restrict__ as2, const float* __restrict__ ad2,
                                                unsigned short* __restrict__ Gb, float* __restrict__ als2,
                                                float* __restrict__ ald2) {
    int tid = threadIdx.x;
    int wv = tid >> 6, lane = tid & 63, lr = lane & 15, quad = lane >> 4;
    int row0 = blockIdx.x * 64 + wv * 16;
    int rowA = row0 + lr;
    unsigned rA = (rowA < N_NODES) ? (unsigned)rowA : (unsigned)(N_NODES - 1);
    f32x4 acc[2];
    acc[0] = (f32x4){0.f, 0.f, 0.f, 0.f};
    acc[1] = (f32x4){0.f, 0.f, 0.f, 0.f};
#pragma unroll
    for (int k0 = 0; k0 < 256; k0 += 32) {
        uint2 d = *(const uint2*)(H2p + rA * 64 + (k0 >> 2) + quad * 2);
        f32x2 f0 = __builtin_amdgcn_cvt_pk_f32_fp8(d.x, false);
        f32x2 f1 = __builtin_amdgcn_cvt_pk_f32_fp8(d.x, true);
        f32x2 f2 = __builtin_amdgcn_cvt_pk_f32_fp8(d.y, false);
        f32x2 f3 = __builtin_amdgcn_cvt_pk_f32_fp8(d.y, true);
        union { uint4 u; s16x8 s; } cv;
        cv.u = pack_bf16_trunc(make_float4(f0.x, f0.y, f1.x, f1.y), make_float4(f2.x, f2.y, f3.x, f3.y));
        s16x8 afrag = cv.s;
        s16x8 b0 = *(const s16x8*)(W2T + lr * 256 + k0 + quad * 8);
        s16x8 b1f = *(const s16x8*)(W2T + (16 + lr) * 256 + k0 + quad * 8);
        acc[0] = __builtin_amdgcn_mfma_f32_16x16x32_bf16(afrag, b0, acc[0], 0, 0, 0);
        acc[1] = __builtin_amdgcn_mfma_f32_16x16x32_bf16(afrag, b1f, acc[1], 0, 0, 0);
    }
    float a2s = as2[lr] * LOG2E, a2s2 = as2[16 + lr] * LOG2E;
    float a2d = ad2[lr] * LOG2E, a2d2 = ad2[16 + lr] * LOG2E;
#pragma unroll
    for (int r = 0; r < 4; ++r) {
        int row = row0 + quad * 4 + r;
        float g0 = acc[0][r], g1 = acc[1][r];
        float s = g0 * a2s + g1 * a2s2;
        float dd = g0 * a2d + g1 * a2d2;
#pragma unroll
        for (int m = 8; m >= 1; m >>= 1) { s += __shfl_xor(s, m); dd += __shfl_xor(dd, m); }
        if (row < N_NODES) {
            Gb[(size_t)row * 32 + lr] = f2bf(g0);
            Gb[(size_t)row * 32 + 16 + lr] = f2bf(g1);
            if (lr == 0) { als2[row] = s; ald2[row] = dd; }
        }
    }
}

// ---------------- Layer-2 aggregation: 16 lanes/node x 2 cols, pk-fma, direct v_exp (round-11 best) --------

__global__ __launch_bounds__(256) void k_agg2(const unsigned short* __restrict__ Gb,
                                              const float* __restrict__ als2,
                                              const float* __restrict__ ald2_, const int* __restrict__ offp,
                                              const int* __restrict__ ecnt,
                                              const unsigned short* __restrict__ esrc, const float* __restrict__ b2,
                                              float* __restrict__ out) {
    int gid = blockIdx.x * 256 + threadIdx.x;
    int node = gid >> 4;
    int colp = gid & 15;            // cols 2*colp, 2*colp+1
    if (node >= N_NODES) return;
    float ald = ald2_[node];        // pre-scaled by LOG2E
    int pstart = offp[node];        // 4-aligned
    int pend = pstart + ecnt[node]; // real end (pads excluded)
    float l = 0.f;
    f32x2 accv = (f32x2){0.f, 0.f};

    auto edge1 = [&](int u0) {
        unsigned gpk = *(const unsigned*)(Gb + (size_t)(unsigned)u0 * 32 + 2 * colp);
        f32x2 g01 = (f32x2){asf(gpk << 16), asf(gpk & 0xffff0000u)};
        float e0 = als2[u0] + ald;
        e0 = fmaxf(e0, NEG_SLOPE * e0);
        float pw0 = __builtin_amdgcn_exp2f(e0);
        l += pw0;
        accv += (f32x2){pw0, pw0} * g01;
    };
    auto quad = [&](unsigned ua, unsigned ub) {
        int u0 = (int)(ua & 0xffffu), u1 = (int)(ua >> 16);
        int u2 = (int)(ub & 0xffffu), u3 = (int)(ub >> 16);
        unsigned g0p = *(const unsigned*)(Gb + (size_t)(unsigned)u0 * 32 + 2 * colp);
        unsigned g1p = *(const unsigned*)(Gb + (size_t)(unsigned)u1 * 32 + 2 * colp);
        unsigned g2p = *(const unsigned*)(Gb + (size_t)(unsigned)u2 * 32 + 2 * colp);
        unsigned g3p = *(const unsigned*)(Gb + (size_t)(unsigned)u3 * 32 + 2 * colp);
        f32x2 e01 = (f32x2){als2[u0], als2[u1]} + (f32x2){ald, ald};
        f32x2 e23 = (f32x2){als2[u2], als2[u3]} + (f32x2){ald, ald};
        f32x2 t01 = e01 * NEG_SLOPE, t23 = e23 * NEG_SLOPE;
        float e0 = fmaxf(e01.x, t01.x), e1 = fmaxf(e01.y, t01.y);
        float e2 = fmaxf(e23.x, t23.x), e3 = fmaxf(e23.y, t23.y);
        float pw0 = __builtin_amdgcn_exp2f(e0), pw1 = __builtin_amdgcn_exp2f(e1);
        float pw2 = __builtin_amdgcn_exp2f(e2), pw3 = __builtin_amdgcn_exp2f(e3);
        l += (pw0 + pw1) + (pw2 + pw3);
        f32x2 g0 = (f32x2){asf(g0p << 16), asf(g0p & 0xffff0000u)};
        f32x2 g1 = (f32x2){asf(g1p << 16), asf(g1p & 0xffff0000u)};
        f32x2 g2 = (f32x2){asf(g2p << 16), asf(g2p & 0xffff0000u)};
        f32x2 g3 = (f32x2){asf(g3p << 16), asf(g3p & 0xffff0000u)};
        accv += (f32x2){pw0, pw0} * g0;
        accv += (f32x2){pw1, pw1} * g1;
        accv += (f32x2){pw2, pw2} * g2;
        accv += (f32x2){pw3, pw3} * g3;
    };

    int p = pstart;
    for (; p + 7 < pend; p += 8) {
        uint2 ua = *(const uint2*)(esrc + p);
        uint2 ub = *(const uint2*)(esrc + p + 4);
        quad(ua.x, ua.y);
        quad(ub.x, ub.y);
    }
    for (; p + 3 < pend; p += 4) {
        uint2 ua = *(const uint2*)(esrc + p);
        quad(ua.x, ua.y);
    }
    for (; p < pend; ++p) edge1(esrc[p]);

    float inv = 1.f / l;
    float2 bb = *(const float2*)(b2 + 2 * colp);
    float o0 = accv.x * inv + bb.x;
    float o1 = accv.y * inv + bb.y;
    float mm = fmaxf(o0, o1);
#pragma unroll
    for (int msk = 8; msk >= 1; msk >>= 1) mm = fmaxf(mm, __shfl_xor(mm, msk));
    float s = __expf(o0 - mm) + __expf(o1 - mm);
#pragma unroll
    for (int msk = 8; msk >= 1; msk >>= 1) s += __shfl_xor(s, msk);
    float ls = logf(s);
    float2 res = make_float2(o0 - mm - ls, o1 - mm - ls);
    *(float2*)(out + (size_t)node * 32 + 2 * colp) = res;
}

// ---------------- launch ----------------

extern "C" void kernel_launch(void* const* d_in, const int* in_sizes, int n_in,
                              void* d_out, int out_size, void* d_ws, size_t ws_size,
                              hipStream_t stream) {
    const float* x   = (const float*)d_in[0];
    const int*   ei  = (const int*)d_in[1];
    const float* W1  = (const float*)d_in[2];
    const float* as1 = (const float*)d_in[3];
    const float* ad1 = (const float*)d_in[4];
    const float* b1  = (const float*)d_in[5];
    const float* W2  = (const float*)d_in[6];
    const float* as2 = (const float*)d_in[7];
    const float* ad2 = (const float*)d_in[8];
    const float* b2  = (const float*)d_in[9];
    float* out = (float*)d_out;

    char* p = (char*)d_ws;
    auto alloc = [&](size_t bytes) {
        char* r = p;
        p += (bytes + 255) & ~(size_t)255;
        return r;
    };
    // workspace ~30 MB (stage aliases h2p; g aliases h8 — disjoint lifetimes)
    unsigned char*  h8  = (unsigned char*)alloc((size_t)(N_NODES + 1) * 256);  // 12.8 MB fp8 h1 (+pad row)
    unsigned char*  h2pr= (unsigned char*)alloc((size_t)N_NODES * 64 * 4);     // 12.8 MB fp8 h2 packed
    unsigned short* wt  = (unsigned short*)alloc((size_t)256 * 256 * 2);       // 128 KB bf16 W1^T
    unsigned short* w2t = (unsigned short*)alloc((size_t)32 * 256 * 2);        // 16 KB bf16 W2^T
    float* als1 = (float*)alloc(((size_t)N_NODES * 4 + 4) * 4);                // +1 pad-sentinel row
    float* ald1 = (float*)alloc((size_t)N_NODES * 4 * 4);
    float* als2 = (float*)alloc((size_t)N_NODES * 4);
    float* ald2 = (float*)alloc((size_t)N_NODES * 4);
    int* bcur    = (int*)alloc(256 * 4);
    int* offp = (int*)alloc((size_t)N_NODES * 4);
    int* ecnt = (int*)alloc((size_t)N_NODES * 4);
    unsigned short* esrc = (unsigned short*)alloc((size_t)ET_PAD_ALLOC * 2);   // 2.2 MB u16, fixed-pitch padded CSR

    // aliases (disjoint lifetimes):
    unsigned* stage = (unsigned*)h2pr;                 // 3.6 MB (pre1 -> pre2; dead before agg1 writes h2p)
    unsigned* h2p = (unsigned*)h2pr;
    unsigned short* g = (unsigned short*)h8;           // 3.2 MB bf16 (written by gemm2m after h8 dead)

    hipMemsetAsync(bcur, 0, 256 * 4, stream);                                   // bcur=0 before pre1
    k_pre1<<<BINB + 289, 256, 0, stream>>>(ei, bcur, stage, W1, W2, wt, w2t, als1, h8);
    k_pre2<<<G1B + NBUK, 256, 0, stream>>>(x, wt, as1, ad1, h8, als1, ald1, stage, bcur, offp, ecnt, esrc);
    k_agg1<<<(N_NODES / 2 + 3) / 4, 256, 0, stream>>>((const uint2*)h8, als1, ald1, offp, ecnt, esrc, b1,
                                                      (uint2*)h2p);
    k_gemm2m<<<(N_NODES + 63) / 64, 256, 0, stream>>>(h2p, w2t, as2, ad2, g, als2, ald2);
    k_agg2<<<(N_NODES * 16 + 255) / 256, 256, 0, stream>>>(g, als2, ald2, offp, ecnt, esrc, b2, out);
}